// Round 16
// baseline (97.845 us; speedup 1.0000x reference)
//
#include <hip/hip_runtime.h>
#include <math.h>

// Problem constants (B, C, H, W) = (16, 256, 64, 64), GROUPS=4, RATIO=2
#define B_   16
#define C_   256
#define H_   64
#define W_   64
#define G_   4
#define HO_  128
#define WO_  128
#define HW_  (H_ * W_)
#define HOWO_ (HO_ * WO_)

// Weights in constant address space -> uniform accesses compile to s_load.
__constant__ float wconst[8 * 32 * 40];   // 40 KB

// ---------------------------------------------------------------------------
// Prep: wcomb[u][i2][40] for wave u (v=u&3, hi=u>>2), channel i=64v+32hi+i2:
//   [0..31]  = w_off[o][i]                     o = 0..31
//   [32..39] = w_scope[v][j][32*hi + i2]       j = 0..7
// ---------------------------------------------------------------------------
__global__ __launch_bounds__(256) void prep_kernel(
    const float* __restrict__ w_off,    // (32, 256)
    const float* __restrict__ w_scope,  // (4, 8, 64)
    float* __restrict__ wout)           // = wconst backing store
{
    const int k = blockIdx.x * 256 + threadIdx.x;   // 10240 total
    if (k >= 8 * 32 * 40) return;
    const int q  = k % 40;
    const int r  = k / 40;
    const int i2 = r & 31;
    const int u  = r >> 5;
    const int v  = u & 3;
    const int hi = u >> 2;
    const int i  = 64 * v + 32 * hi + i2;
    float val;
    if (q < 32) val = w_off[q * 256 + i];
    else        val = w_scope[v * 512 + (q - 32) * 64 + 32 * hi + i2];
    wout[k] = val;
}

// ---------------------------------------------------------------------------
// Persistent fused kernel: grid 512, each block owns 2 h-adjacent tiles
// (b, h0) and (b, h0+1). Tile-1 x-loads are issued into registers right
// after tile-0's conv consumes them -> latency hides under tile-0's
// reduce+sample. Conv/reduce/sample internals = R11/R14 proven versions.
// 2 blocks/CU x 8 waves = 16 waves/CU (the measured sweet spot).
// ---------------------------------------------------------------------------
__global__ __launch_bounds__(512, 4) void fused_kernel(
    const float* __restrict__ x,        // (B, 256, 64, 64)
    const float* __restrict__ b_off,    // (32,)
    const float* __restrict__ b_scope,  // (32,)
    float* __restrict__ out)            // (B, 256, 128, 128)
{
    __shared__ float4 red[4][8][64];    // [slot][chunk][pixel] 32 KB (reused)
    __shared__ float4 aux[8][64];       // scp partials, then coords; 8 KB

    const int tid = threadIdx.x;
    const int u   = __builtin_amdgcn_readfirstlane(tid >> 6);  // wave id
    const int w   = tid & 63;                                  // pixel in row

    // XCD-bijective tile pairing: XCD k = blockIdx%8 owns b in {2k, 2k+1};
    // block handles rows h0, h0+1 (adjacent -> L1/L2 reuse across tiles).
    const int xcd = blockIdx.x & 7;
    const int j   = blockIdx.x >> 3;        // 0..63
    const int b   = 2 * xcd + (j >> 5);
    const int h0  = 2 * (j & 31);

    const int v   = u & 3;              // group
    const int hi  = u >> 2;             // channel half

    const float* xq = x + (size_t)b * C_ * HW_ +
                      (size_t)(64 * v + 32 * hi) * HW_ + h0 * W_ + w;
    const int wbase0 = u * (32 * 40);   // uniform

    // tile-0 x prefetch (32 outstanding coalesced loads)
    float xv[32];
#pragma unroll
    for (int i2 = 0; i2 < 32; ++i2) xv[i2] = xq[(size_t)i2 * HW_];

#pragma unroll
    for (int t = 0; t < 2; ++t) {
        const int h = h0 + t;

        float offp[32];
        float scp[8];
#pragma unroll
        for (int jj = 0; jj < 32; ++jj) offp[jj] = 0.f;
#pragma unroll
        for (int jj = 0; jj < 8; ++jj) scp[jj] = 0.f;

        // conv FMAs: xv register array -> FULL unroll (static indices only)
#pragma unroll
        for (int i2 = 0; i2 < 32; ++i2) {
            const float xvv = xv[i2];
            const int wb = wbase0 + i2 * 40;     // uniform -> s_load from AS4
#pragma unroll
            for (int jj = 0; jj < 32; ++jj) offp[jj] += xvv * wconst[wb + jj];
#pragma unroll
            for (int jj = 0; jj < 8; ++jj)  scp[jj] += xvv * wconst[wb + 32 + jj];
        }

        // issue tile-1 x loads now: they drain under tile-0 reduce+sample
        if (t == 0) {
#pragma unroll
            for (int i2 = 0; i2 < 32; ++i2)
                xv[i2] = xq[(size_t)i2 * HW_ + W_];
        }

        // barrier: previous tile's sample done reading aux/red
        __syncthreads();

        // ---- round 1: hi waves publish into red[v]; lo waves absorb ----
        if (hi) {
#pragma unroll
            for (int jj = 0; jj < 8; ++jj)
                red[v][jj][w] = make_float4(offp[4 * jj + 0], offp[4 * jj + 1],
                                            offp[4 * jj + 2], offp[4 * jj + 3]);
            aux[2 * v + 0][w] = make_float4(scp[0], scp[1], scp[2], scp[3]);
            aux[2 * v + 1][w] = make_float4(scp[4], scp[5], scp[6], scp[7]);
        }
        __syncthreads();
        if (!hi) {
            // lo wave v is the ONLY reader of red[v]; read, then overwrite
#pragma unroll
            for (int jj = 0; jj < 8; ++jj) {
                const float4 p = red[v][jj][w];
                offp[4 * jj + 0] += p.x; offp[4 * jj + 1] += p.y;
                offp[4 * jj + 2] += p.z; offp[4 * jj + 3] += p.w;
            }
            const float4 s0 = aux[2 * v + 0][w];
            const float4 s1 = aux[2 * v + 1][w];
            scp[0] += s0.x; scp[1] += s0.y; scp[2] += s0.z; scp[3] += s0.w;
            scp[4] += s1.x; scp[5] += s1.y; scp[6] += s1.z; scp[7] += s1.w;
            // round-2 publish (slot reuse)
#pragma unroll
            for (int jj = 0; jj < 8; ++jj)
                red[v][jj][w] = make_float4(offp[4 * jj + 0], offp[4 * jj + 1],
                                            offp[4 * jj + 2], offp[4 * jj + 3]);
        }
        __syncthreads();
        if (!hi) {
            float4 a = make_float4(0.f, 0.f, 0.f, 0.f);
            float4 c = make_float4(0.f, 0.f, 0.f, 0.f);
#pragma unroll
            for (int tt = 0; tt < 4; ++tt) {
                const float4 pa = red[tt][2 * v + 0][w];
                const float4 pc = red[tt][2 * v + 1][w];
                a.x += pa.x; a.y += pa.y; a.z += pa.z; a.w += pa.w;
                c.x += pc.x; c.y += pc.y; c.z += pc.z; c.w += pc.w;
            }
            const float ao[8] = {a.x, a.y, a.z, a.w, c.x, c.y, c.z, c.w};
            float f[8];
#pragma unroll
            for (int jj = 0; jj < 8; ++jj) {
                const float offv = ao[jj] + b_off[8 * v + jj];
                const float scv  = scp[jj] + b_scope[8 * v + jj];
                f[jj] = offv * 0.5f / (1.f + expf(-scv));
            }
            // coords for group v: aux[2v+r1][w] = (ix0,iy0,ix1,iy1), wo=2w,2w+1
#pragma unroll
            for (int r1 = 0; r1 < 2; ++r1) {
                const float hoF = (float)(2 * h + r1);
                float ix0 = ((float)(2 * w + 0) - 0.5f + f[2 * r1 + 0]) * 0.5f;
                float iy0 = (hoF - 0.5f + f[4 + 2 * r1 + 0]) * 0.5f;
                float ix1 = ((float)(2 * w + 1) - 0.5f + f[2 * r1 + 1]) * 0.5f;
                float iy1 = (hoF - 0.5f + f[4 + 2 * r1 + 1]) * 0.5f;
                ix0 = fminf(fmaxf(ix0, 0.f), (float)(W_ - 1));
                iy0 = fminf(fmaxf(iy0, 0.f), (float)(H_ - 1));
                ix1 = fminf(fmaxf(ix1, 0.f), (float)(W_ - 1));
                iy1 = fminf(fmaxf(iy1, 0.f), (float)(H_ - 1));
                aux[2 * v + r1][w] = make_float4(ix0, iy0, ix1, iy1);
            }
        }
        __syncthreads();

        // ---------------- phase 2: bilinear sampling (R11 verbatim) ------
        const int wo = tid & 127;
        const int z  = (tid >> 7) & 1;
        const int gh = tid >> 8;            // group half
        const int ho = 2 * h + z;

        const float2* cbase = (const float2*)&aux[0][0];
        const float* xb0 = x + (size_t)b * C_ * HW_;
        float* ob0 = out + (size_t)b * C_ * HOWO_ + ho * WO_ + wo;

#pragma unroll
        for (int gg = 0; gg < 2; ++gg) {
            const int g = 2 * gh + gg;
            const float2 c = cbase[(g * 2 + z) * 128 + wo];
            const float ix = c.x, iy = c.y;

            const float x0f = floorf(ix);
            const float y0f = floorf(iy);
            const float wx = ix - x0f;
            const float wy = iy - y0f;
            int x0 = (int)x0f;
            int y0 = (int)y0f;
            x0 = max(0, min(x0, W_ - 1));
            y0 = max(0, min(y0, H_ - 1));
            const int x1 = min(x0 + 1, W_ - 1);
            const int y1 = min(y0 + 1, H_ - 1);

            const float w00 = (1.f - wy) * (1.f - wx);
            const float w01 = (1.f - wy) * wx;
            const float w10 = wy * (1.f - wx);
            const float w11 = wy * wx;

            const int p00 = y0 * W_ + x0;
            const int p01 = y0 * W_ + x1;
            const int p10 = y1 * W_ + x0;
            const int p11 = y1 * W_ + x1;

            const float* xb = xb0 + (size_t)g * HW_;
            float* ob = ob0 + (size_t)g * HOWO_;

#pragma unroll 4
            for (int cc = 0; cc < 64; ++cc) {
                const float* pl = xb + (size_t)cc * 4 * HW_;
                const float val = pl[p00] * w00 + pl[p01] * w01 +
                                  pl[p10] * w10 + pl[p11] * w11;
                // write-once/never-read: NT store keeps L2/L3 for x
                __builtin_nontemporal_store(val, &ob[(size_t)cc * 4 * HOWO_]);
            }
        }
    }
}

// ---------------------------------------------------------------------------
extern "C" void kernel_launch(void* const* d_in, const int* in_sizes, int n_in,
                              void* d_out, int out_size, void* d_ws, size_t ws_size,
                              hipStream_t stream) {
    const float* x       = (const float*)d_in[0];
    const float* w_off   = (const float*)d_in[1];
    const float* b_off   = (const float*)d_in[2];
    const float* w_scope = (const float*)d_in[3];
    const float* b_scope = (const float*)d_in[4];
    float* out = (float*)d_out;

    void* wsym = nullptr;
    (void)hipGetSymbolAddress(&wsym, HIP_SYMBOL(wconst));

    prep_kernel<<<dim3(40), 256, 0, stream>>>(w_off, w_scope, (float*)wsym);
    fused_kernel<<<dim3(512), 512, 0, stream>>>(x, b_off, b_scope, out);
}